// Round 5
// baseline (299.005 us; speedup 1.0000x reference)
//
#include <hip/hip_runtime.h>

#define NB 8192
#define ND 512
#define QB 64
#define KB 64
#define NTILES (NB / KB)          // 128
#define TILE_BYTES (KB * ND * 2)  // 65536

typedef unsigned short u16;
typedef unsigned int u32;
typedef __attribute__((ext_vector_type(8))) short bf16x8;
typedef __attribute__((ext_vector_type(4))) float f32x4;

__device__ inline u16 f2bf(float f) {
  u32 u = __float_as_uint(f);
  return (u16)((u + 0x7fffu + ((u >> 16) & 1u)) >> 16);
}

// ---------------- prep1: reciprocal row norms ----------------
__global__ __launch_bounds__(256) void prep_norms(const float* __restrict__ x,
                                                  float* __restrict__ norms) {
  int row = blockIdx.x * 4 + (threadIdx.x >> 6);
  int lane = threadIdx.x & 63;
  const float4* xr = reinterpret_cast<const float4*>(x + (size_t)row * ND);
  float4 a = xr[lane];
  float4 b = xr[64 + lane];
  float ss = a.x * a.x + a.y * a.y + a.z * a.z + a.w * a.w +
             b.x * b.x + b.y * b.y + b.z * b.z + b.w * b.w;
  ss += __shfl_xor(ss, 1);  ss += __shfl_xor(ss, 2);  ss += __shfl_xor(ss, 4);
  ss += __shfl_xor(ss, 8);  ss += __shfl_xor(ss, 16); ss += __shfl_xor(ss, 32);
  if (lane == 0) norms[row] = 1.0f / fmaxf(sqrtf(ss), 1e-12f);
}

// ---------------- prep2: pre-swizzled bf16 tile images (64-kv tiles) ----------------
// Kimg element (kv,d):        byte = (kv*1024 + d*2) ^ ((kv&7)<<4)   [linear in kv]
// Vimg element (d,kv) per 64-kv tile: byte = (d*128 + kv*2) ^ ((d&7)<<4)
__global__ __launch_bounds__(256) void prep_images(const float* __restrict__ x,
                                                   u16* __restrict__ Kimg,
                                                   u16* __restrict__ Vimg) {
  __shared__ u16 Lt[KB * ND];  // 64KB, Kimg-layout copy of this tile
  const int t = blockIdx.x;
  const int tid = threadIdx.x;

  {
    int kv = tid >> 2, d0 = (tid & 3) * 128;
    const float* src = x + (size_t)(t * KB + kv) * ND + d0;
    char* kbase = (char*)Kimg + (size_t)t * TILE_BYTES;
#pragma unroll
    for (int j = 0; j < 16; ++j) {
      float4 f0 = *(const float4*)(src + j * 8);
      float4 f1 = *(const float4*)(src + j * 8 + 4);
      union { u16 u[8]; uint4 v; } pk;
      pk.u[0] = f2bf(f0.x); pk.u[1] = f2bf(f0.y); pk.u[2] = f2bf(f0.z); pk.u[3] = f2bf(f0.w);
      pk.u[4] = f2bf(f1.x); pk.u[5] = f2bf(f1.y); pk.u[6] = f2bf(f1.z); pk.u[7] = f2bf(f1.w);
      int byte = (kv * 1024 + (d0 + j * 8) * 2) ^ ((kv & 7) << 4);
      *(uint4*)(kbase + byte) = pk.v;
      *(uint4*)((char*)Lt + byte) = pk.v;
    }
  }
  __syncthreads();
  {
    char* vbase = (char*)Vimg + (size_t)t * TILE_BYTES;
#pragma unroll
    for (int i = 0; i < 16; ++i) {
      int gid = tid + 256 * i;
      int d = gid >> 3, kv0 = (gid & 7) * 8;
      union { u16 u[8]; uint4 v; } o;
#pragma unroll
      for (int k = 0; k < 8; ++k) {
        int sb = ((kv0 + k) * 1024 + d * 2) ^ (((kv0 + k) & 7) << 4);
        o.u[k] = *(const u16*)((const char*)Lt + sb);
      }
      int byte = (d * 128 + kv0 * 2) ^ ((d & 7) << 4);
      *(uint4*)(vbase + byte) = o.v;
    }
  }
}

// ---------------- fused attention ----------------
// NCH=2: grid 256, partials per KV-half.  NCH=1: grid 128, direct out.
template <int NCH>
__global__ __launch_bounds__(512, 2) void attn_kernel(const float* __restrict__ x,
                                                      const u16* __restrict__ Kimg,
                                                      const u16* __restrict__ Vimg,
                                                      const float* __restrict__ norms,
                                                      float* __restrict__ Opart,
                                                      float* __restrict__ Zpart,
                                                      float* __restrict__ out) {
  __shared__ u16 Kl[KB * ND];  // 64KB: always K tile
  __shared__ u16 Vl[KB * ND];  // 64KB: always V tile
  __shared__ u16 Pl[QB * KB];  // 8KB: byte = (q*128+kv*2) ^ ((q&7)<<4)
  __shared__ float Zred[256];
  __shared__ float Zfin[QB];

  const int tid = threadIdx.x;
  const int w = tid >> 6;
  const int l = tid & 63;
  const int bid = blockIdx.x;

  int chunk, qblk;
  if constexpr (NCH == 2) {
    chunk = (bid >> 2) & 1;
    qblk = (bid & 3) * 32 + (bid >> 3);
  } else {
    chunk = 0;
    qblk = (bid & 7) * 16 + (bid >> 3);
  }
  const int CT = NTILES / NCH;                 // tiles per chunk
  const int CHUNK = NB / NCH;                  // kv rows per chunk
  const int tile0 = chunk * CT;

  const int pq = w & 1;    // phase-1 q-pair (q-tiles pq*2, pq*2+1)
  const int tkv = w >> 1;  // phase-1 kv sub-tile (0..3)

  // ---- Q fragments: two q16 sub-tiles, normalized bf16 baked from f32
  bf16x8 qf[2][16];
#pragma unroll
  for (int a = 0; a < 2; ++a) {
    int qrow = qblk * QB + (pq * 2 + a) * 16 + (l & 15);
    float rnq = norms[qrow];
    const float* xr = x + (size_t)qrow * ND;
#pragma unroll
    for (int ks = 0; ks < 16; ++ks) {
      int d0 = ks * 32 + (l >> 4) * 8;
      float4 f0 = *(const float4*)(xr + d0);
      float4 f1 = *(const float4*)(xr + d0 + 4);
      union { u16 u[8]; bf16x8 v; } pk;
      pk.u[0] = f2bf(f0.x * rnq); pk.u[1] = f2bf(f0.y * rnq);
      pk.u[2] = f2bf(f0.z * rnq); pk.u[3] = f2bf(f0.w * rnq);
      pk.u[4] = f2bf(f1.x * rnq); pk.u[5] = f2bf(f1.y * rnq);
      pk.u[6] = f2bf(f1.z * rnq); pk.u[7] = f2bf(f1.w * rnq);
      qf[a][ks] = pk.v;
    }
  }

  auto stageK = [&](int tg) {
    size_t toff = (size_t)tg * TILE_BYTES;
#pragma unroll
    for (int j = 0; j < 8; ++j) {
      const char* src = (const char*)Kimg + toff + (w * 8 + j) * 1024 + l * 16;
      char* dst = (char*)Kl + (w * 8 + j) * 1024;
      __builtin_amdgcn_global_load_lds((const void*)src, (void*)dst, 16, 0, 0);
    }
  };
  auto stageV = [&](int tg) {
    size_t toff = (size_t)tg * TILE_BYTES;
#pragma unroll
    for (int j = 0; j < 8; ++j) {
      const char* src = (const char*)Vimg + toff + (w * 8 + j) * 1024 + l * 16;
      char* dst = (char*)Vl + (w * 8 + j) * 1024;
      __builtin_amdgcn_global_load_lds((const void*)src, (void*)dst, 16, 0, 0);
    }
  };

  // prologue: K0 resident; V0 in flight
  stageK(tile0);
  asm volatile("s_waitcnt vmcnt(0)" ::: "memory");
  __builtin_amdgcn_s_barrier();
  __builtin_amdgcn_sched_barrier(0);
  stageV(tile0);

  f32x4 oacc[4][4];
#pragma unroll
  for (int a = 0; a < 4; ++a)
#pragma unroll
    for (int b = 0; b < 4; ++b) oacc[a][b] = (f32x4){0.f, 0.f, 0.f, 0.f};
  float za[2] = {0.f, 0.f};

  const int kv = tkv * 16 + (l & 15);
  const int krowbase = kv * 1024;
  const int kswz = (kv & 7) << 4;
  const int hi16 = (l >> 4) * 16;

  for (int t = 0; t < CT; ++t) {
    // ---- phase 1: S^T(kv16 x q16 x2) = K . Q^T; each K read feeds 2 MFMAs
    f32x4 acc0 = {0.f, 0.f, 0.f, 0.f}, acc1 = {0.f, 0.f, 0.f, 0.f};
    {
      const char* kb = (const char*)Kl;
#pragma unroll
      for (int ks = 0; ks < 16; ++ks) {
        bf16x8 kf = *(const bf16x8*)(kb + ((krowbase + ks * 64 + hi16) ^ kswz));
        acc0 = __builtin_amdgcn_mfma_f32_16x16x32_bf16(kf, qf[0][ks], acc0, 0, 0, 0);
        acc1 = __builtin_amdgcn_mfma_f32_16x16x32_bf16(kf, qf[1][ks], acc1, 0, 0, 0);
      }
    }
    // ---- epilogue: cosine scale by rn_k, exp, Z, pack P
    {
      int kvb = tkv * 16 + (l >> 4) * 4;
      float4 rn4 = *(const float4*)(norms + chunk * CHUNK + t * KB + kvb);
#pragma unroll
      for (int a = 0; a < 2; ++a) {
        const f32x4& ac = a ? acc1 : acc0;
        float p0 = __expf(ac[0] * rn4.x);
        float p1 = __expf(ac[1] * rn4.y);
        float p2 = __expf(ac[2] * rn4.z);
        float p3 = __expf(ac[3] * rn4.w);
        za[a] += (p0 + p1) + (p2 + p3);
        u32 w01, w23;
        asm("v_cvt_pk_bf16_f32 %0, %1, %2" : "=v"(w01) : "v"(p0), "v"(p1));
        asm("v_cvt_pk_bf16_f32 %0, %1, %2" : "=v"(w23) : "v"(p2), "v"(p3));
        int q = (pq * 2 + a) * 16 + (l & 15);
        int pbyte = (q * 128 + kvb * 2) ^ ((q & 7) << 4);
        *(uint2*)((char*)Pl + pbyte) = (uint2){w01, w23};
      }
    }
    asm volatile("s_waitcnt vmcnt(0) lgkmcnt(0)" ::: "memory");  // V_t landed; P done
    __builtin_amdgcn_s_barrier();
    __builtin_amdgcn_sched_barrier(0);
    if (t + 1 < CT) stageK(tile0 + t + 1);  // flies under phase 2

    // ---- phase 2: O += P . V (wave owns d-block w*64; K-dim 64 = 2 steps)
    {
      const char* plb = (const char*)Pl;
      bf16x8 pa[4][2];
#pragma unroll
      for (int q2 = 0; q2 < 4; ++q2) {
        int qr = q2 * 16 + (l & 15);
        int qswz = (qr & 7) << 4;
#pragma unroll
        for (int ks = 0; ks < 2; ++ks)
          pa[q2][ks] = *(const bf16x8*)(plb + ((qr * 128 + ks * 64 + hi16) ^ qswz));
      }
      const char* vb = (const char*)Vl;
#pragma unroll
      for (int dt = 0; dt < 4; ++dt) {
        int d = w * 64 + dt * 16 + (l & 15);
        int vswz = (d & 7) << 4;
#pragma unroll
        for (int ks = 0; ks < 2; ++ks) {
          bf16x8 vf = *(const bf16x8*)(vb + ((d * 128 + ks * 64 + hi16) ^ vswz));
#pragma unroll
          for (int q2 = 0; q2 < 4; ++q2)
            oacc[q2][dt] =
                __builtin_amdgcn_mfma_f32_16x16x32_bf16(pa[q2][ks], vf, oacc[q2][dt], 0, 0, 0);
        }
      }
    }
    asm volatile("s_waitcnt vmcnt(0) lgkmcnt(0)" ::: "memory");  // K_{t+1} landed; Vl free
    __builtin_amdgcn_s_barrier();
    __builtin_amdgcn_sched_barrier(0);
    if (t + 1 < CT) stageV(tile0 + t + 1);  // flies under next phase 1
  }

  // ---- Z reduction: za[a] covers q-tile pq*2+a, cols (l&15), partial over kv16 tkv
  {
#pragma unroll
    for (int a = 0; a < 2; ++a) {
      float s = za[a];
      s += __shfl_xor(s, 16);
      s += __shfl_xor(s, 32);
      if (l < 16) Zred[w * 32 + a * 16 + l] = s;
    }
  }
  __syncthreads();

  if constexpr (NCH == 2) {
    if (tid < QB) {
      int g = tid >> 4, p_ = g >> 1, a_ = g & 1;
      float s = 0.f;
#pragma unroll
      for (int tk = 0; tk < 4; ++tk) s += Zred[(tk * 2 + p_) * 32 + a_ * 16 + (tid & 15)];
      Zpart[chunk * NB + qblk * QB + tid] = s;
    }
    float* op = Opart + (size_t)chunk * NB * ND;
#pragma unroll
    for (int q2 = 0; q2 < 4; ++q2)
#pragma unroll
      for (int dt = 0; dt < 4; ++dt) {
        int d = w * 64 + dt * 16 + (l & 15);
#pragma unroll
        for (int r = 0; r < 4; ++r) {
          int q = qblk * QB + q2 * 16 + (l >> 4) * 4 + r;
          op[(size_t)q * ND + d] = oacc[q2][dt][r];
        }
      }
  } else {
    if (tid < QB) {
      int g = tid >> 4, p_ = g >> 1, a_ = g & 1;
      float s = 0.f;
#pragma unroll
      for (int tk = 0; tk < 4; ++tk) s += Zred[(tk * 2 + p_) * 32 + a_ * 16 + (tid & 15)];
      Zfin[tid] = s;
    }
    __syncthreads();
#pragma unroll
    for (int q2 = 0; q2 < 4; ++q2) {
      float rz[4];
#pragma unroll
      for (int r = 0; r < 4; ++r) rz[r] = 1.0f / Zfin[q2 * 16 + (l >> 4) * 4 + r];
#pragma unroll
      for (int dt = 0; dt < 4; ++dt) {
        int d = w * 64 + dt * 16 + (l & 15);
#pragma unroll
        for (int r = 0; r < 4; ++r) {
          int q = qblk * QB + q2 * 16 + (l >> 4) * 4 + r;
          out[(size_t)q * ND + d] = oacc[q2][dt][r] * rz[r];
        }
      }
    }
  }
}

// ---------------- combine (fast path): out = (O0+O1)/(Z0+Z1) ----------------
__global__ __launch_bounds__(256) void combine_kernel(const float* __restrict__ Opart,
                                                      const float* __restrict__ Zpart,
                                                      float* __restrict__ out) {
  size_t idx = ((size_t)blockIdx.x * 256 + threadIdx.x) * 4;
  int row = (int)(idx >> 9);
  float rz = 1.0f / (Zpart[row] + Zpart[NB + row]);
  float4 a = *(const float4*)(Opart + idx);
  float4 b = *(const float4*)(Opart + (size_t)NB * ND + idx);
  float4 o = {(a.x + b.x) * rz, (a.y + b.y) * rz, (a.z + b.z) * rz, (a.w + b.w) * rz};
  *(float4*)(out + idx) = o;
}

extern "C" void kernel_launch(void* const* d_in, const int* in_sizes, int n_in,
                              void* d_out, int out_size, void* d_ws, size_t ws_size,
                              hipStream_t stream) {
  const float* x = (const float*)d_in[0];
  float* outp = (float*)d_out;

  char* ws = (char*)d_ws;
  const size_t img_bytes = (size_t)NB * ND * 2;  // 8 MB each
  float* norms = (float*)ws;                     // 32 KB
  u16* Kimg = (u16*)(ws + 32768);
  u16* Vimg = (u16*)(ws + 32768 + img_bytes);
  size_t base = 32768 + 2 * img_bytes;           // 16.03 MB
  float* Zpart = (float*)(ws + base);            // 64 KB
  float* Opart = (float*)(ws + base + 65536);    // 32 MB
  size_t need = base + 65536 + (size_t)2 * NB * ND * 4;

  prep_norms<<<NB / 4, 256, 0, stream>>>(x, norms);
  prep_images<<<NTILES, 256, 0, stream>>>(x, Kimg, Vimg);
  if (ws_size >= need) {
    attn_kernel<2><<<256, 512, 0, stream>>>(x, Kimg, Vimg, norms, Opart, Zpart, nullptr);
    combine_kernel<<<(NB * ND) / 1024, 256, 0, stream>>>(Opart, Zpart, outp);
  } else {
    attn_kernel<1><<<128, 512, 0, stream>>>(x, Kimg, Vimg, norms, nullptr, nullptr, outp);
  }
}

// Round 7
// 287.774 us; speedup vs baseline: 1.0390x; 1.0390x over previous
//
#include <hip/hip_runtime.h>

#define NB 8192
#define ND 512
#define QB 64
#define KB 64
#define NTILES (NB / KB)          // 128
#define TILE_BYTES (KB * ND * 2)  // 65536

typedef unsigned short u16;
typedef unsigned int u32;
typedef __attribute__((ext_vector_type(8))) short bf16x8;
typedef __attribute__((ext_vector_type(4))) float f32x4;

__device__ inline u16 f2bf(float f) {
  u32 u = __float_as_uint(f);
  return (u16)((u + 0x7fffu + ((u >> 16) & 1u)) >> 16);
}

// ---------------- prep1: reciprocal row norms ----------------
__global__ __launch_bounds__(256) void prep_norms(const float* __restrict__ x,
                                                  float* __restrict__ norms) {
  int row = blockIdx.x * 4 + (threadIdx.x >> 6);
  int lane = threadIdx.x & 63;
  const float4* xr = reinterpret_cast<const float4*>(x + (size_t)row * ND);
  float4 a = xr[lane];
  float4 b = xr[64 + lane];
  float ss = a.x * a.x + a.y * a.y + a.z * a.z + a.w * a.w +
             b.x * b.x + b.y * b.y + b.z * b.z + b.w * b.w;
  ss += __shfl_xor(ss, 1);  ss += __shfl_xor(ss, 2);  ss += __shfl_xor(ss, 4);
  ss += __shfl_xor(ss, 8);  ss += __shfl_xor(ss, 16); ss += __shfl_xor(ss, 32);
  if (lane == 0) norms[row] = 1.0f / fmaxf(sqrtf(ss), 1e-12f);
}

// ---------------- prep2: K tile images (LDS-swizzled) + V fragment stream ----------------
// Kimg element (kv,d): tile byte (kv*1024 + d*2) ^ ((kv&7)<<4)
// Vfrag: granule gid in tile holds V^T fragment for
//        d = (gid>>9)*64 + ((gid>>7)&3)*16 + (gid&15), kv0 = ((gid>>6)&1)*32 + ((gid>>4)&3)*8
__global__ __launch_bounds__(256) void prep_images(const float* __restrict__ x,
                                                   u16* __restrict__ Kimg,
                                                   u16* __restrict__ Vfrag) {
  __shared__ u16 Lt[KB * ND];  // 64KB, Kimg-layout copy of this tile
  const int t = blockIdx.x;
  const int tid = threadIdx.x;

  {
    int kv = tid >> 2, d0 = (tid & 3) * 128;
    const float* src = x + (size_t)(t * KB + kv) * ND + d0;
    char* kbase = (char*)Kimg + (size_t)t * TILE_BYTES;
#pragma unroll
    for (int j = 0; j < 16; ++j) {
      float4 f0 = *(const float4*)(src + j * 8);
      float4 f1 = *(const float4*)(src + j * 8 + 4);
      union { u16 u[8]; uint4 v; } pk;
      pk.u[0] = f2bf(f0.x); pk.u[1] = f2bf(f0.y); pk.u[2] = f2bf(f0.z); pk.u[3] = f2bf(f0.w);
      pk.u[4] = f2bf(f1.x); pk.u[5] = f2bf(f1.y); pk.u[6] = f2bf(f1.z); pk.u[7] = f2bf(f1.w);
      int byte = (kv * 1024 + (d0 + j * 8) * 2) ^ ((kv & 7) << 4);
      *(uint4*)(kbase + byte) = pk.v;
      *(uint4*)((char*)Lt + byte) = pk.v;
    }
  }
  __syncthreads();
  {
    char* vbase = (char*)Vfrag + (size_t)t * TILE_BYTES;
#pragma unroll
    for (int i = 0; i < 16; ++i) {
      int gid = tid + 256 * i;  // [0,4096) 16B granules
      int d = (gid >> 9) * 64 + (((gid >> 7) & 3) * 16) + (gid & 15);
      int kv0 = ((gid >> 6) & 1) * 32 + ((gid >> 4) & 3) * 8;
      union { u16 u[8]; uint4 v; } o;
#pragma unroll
      for (int k = 0; k < 8; ++k) {
        int sb = ((kv0 + k) * 1024 + d * 2) ^ (((kv0 + k) & 7) << 4);
        o.u[k] = *(const u16*)((const char*)Lt + sb);
      }
      *(uint4*)(vbase + gid * 16) = o.v;
    }
  }
}

// ---------------- fused attention ----------------
// NCH=2: grid 256, f32 partials per KV-half.  NCH=1: grid 128, direct out.
template <int NCH>
__global__ __launch_bounds__(512, 2) void attn_kernel(const float* __restrict__ x,
                                                      const u16* __restrict__ Kimg,
                                                      const u16* __restrict__ Vfrag,
                                                      const float* __restrict__ norms,
                                                      float* __restrict__ Opart,
                                                      float* __restrict__ Zpart,
                                                      float* __restrict__ out) {
  __shared__ u16 Kl[2][KB * ND];            // 128KB, double-buffered K
  __shared__ u16 Pl[QB * KB];               // 8KB: byte = (q*128+kv*2) ^ ((q&7)<<4)
  __shared__ float Nl[(NCH == 2) ? 4096 : 4];  // chunk rnorms (NCH==2)
  __shared__ float Zred[256];
  __shared__ float Zfin[QB];

  const int tid = threadIdx.x;
  const int w = tid >> 6;
  const int l = tid & 63;
  const int bid = blockIdx.x;

  int chunk, qblk;
  if constexpr (NCH == 2) {
    chunk = (bid >> 2) & 1;
    qblk = (bid & 3) * 32 + (bid >> 3);
  } else {
    chunk = 0;
    qblk = (bid & 7) * 16 + (bid >> 3);
  }
  const int CT = NTILES / NCH;
  const int CHUNK = NB / NCH;
  const int tile0 = chunk * CT;

  const int pq = w & 1;    // phase-1 q-pair
  const int tkv = w >> 1;  // phase-1 kv sub-tile (0..3)

  // ---- Q fragments: two q16 sub-tiles, normalized bf16 baked from f32
  bf16x8 qf[2][16];
#pragma unroll
  for (int a = 0; a < 2; ++a) {
    int qrow = qblk * QB + (pq * 2 + a) * 16 + (l & 15);
    float rnq = norms[qrow];
    const float* xr = x + (size_t)qrow * ND;
#pragma unroll
    for (int ks = 0; ks < 16; ++ks) {
      int d0 = ks * 32 + (l >> 4) * 8;
      float4 f0 = *(const float4*)(xr + d0);
      float4 f1 = *(const float4*)(xr + d0 + 4);
      union { u16 u[8]; bf16x8 v; } pk;
      pk.u[0] = f2bf(f0.x * rnq); pk.u[1] = f2bf(f0.y * rnq);
      pk.u[2] = f2bf(f0.z * rnq); pk.u[3] = f2bf(f0.w * rnq);
      pk.u[4] = f2bf(f1.x * rnq); pk.u[5] = f2bf(f1.y * rnq);
      pk.u[6] = f2bf(f1.z * rnq); pk.u[7] = f2bf(f1.w * rnq);
      qf[a][ks] = pk.v;
    }
  }

  // ---- chunk rnorms -> LDS (epilogue reads become LDS, not VMEM)
  if constexpr (NCH == 2) {
    const float4* ns = (const float4*)(norms + chunk * CHUNK);
    float4 n0 = ns[tid * 2], n1 = ns[tid * 2 + 1];
    *(float4*)&Nl[tid * 8] = n0;
    *(float4*)&Nl[tid * 8 + 4] = n1;
  }

  auto stageK = [&](int tg, int b) {
    size_t toff = (size_t)tg * TILE_BYTES;
#pragma unroll
    for (int j = 0; j < 8; ++j) {
      const char* src = (const char*)Kimg + toff + (w * 8 + j) * 1024 + l * 16;
      char* dst = (char*)&Kl[b][0] + (w * 8 + j) * 1024;
      __builtin_amdgcn_global_load_lds((const void*)src, (void*)dst, 16, 0, 0);
    }
  };

  // ---- prologue: K(0) staged and drained
  stageK(tile0, 0);
  asm volatile("s_waitcnt vmcnt(0) lgkmcnt(0)" ::: "memory");
  __builtin_amdgcn_s_barrier();
  __builtin_amdgcn_sched_barrier(0);

  f32x4 oacc[4][4];
#pragma unroll
  for (int a = 0; a < 4; ++a)
#pragma unroll
    for (int b = 0; b < 4; ++b) oacc[a][b] = (f32x4){0.f, 0.f, 0.f, 0.f};
  float za[2] = {0.f, 0.f};

  const int kv = tkv * 16 + (l & 15);
  const int krowbase = kv * 1024;
  const int kswz = (kv & 7) << 4;
  const int hi16 = (l >> 4) * 16;
  const char* vsrc_base = (const char*)Vfrag + (size_t)w * 8192 + (size_t)l * 16;

  for (int t = 0; t < CT; ++t) {
    const int buf = t & 1;

    // ---- issue V(t) register loads (consumed in phase 2; compiler-counted wait)
    uint4 vreg[8];
    {
      const char* vs = vsrc_base + (size_t)(tile0 + t) * TILE_BYTES;
#pragma unroll
      for (int j = 0; j < 8; ++j) vreg[j] = *(const uint4*)(vs + j * 1024);
    }
    // ---- issue K(t+1) stage; drained at end of this iteration (full-iter window)
    if (t + 1 < CT) stageK(tile0 + t + 1, buf ^ 1);

    // ---- phase 1: S^T(kv16 x q16 x2) = K . Q^T; each K read feeds 2 MFMAs
    f32x4 acc0 = {0.f, 0.f, 0.f, 0.f}, acc1 = {0.f, 0.f, 0.f, 0.f};
    {
      const char* kb = (const char*)&Kl[buf][0];
#pragma unroll
      for (int ks = 0; ks < 16; ++ks) {
        bf16x8 kf = *(const bf16x8*)(kb + ((krowbase + ks * 64 + hi16) ^ kswz));
        acc0 = __builtin_amdgcn_mfma_f32_16x16x32_bf16(kf, qf[0][ks], acc0, 0, 0, 0);
        acc1 = __builtin_amdgcn_mfma_f32_16x16x32_bf16(kf, qf[1][ks], acc1, 0, 0, 0);
      }
    }
    // ---- epilogue: cosine scale by rn_k, exp, Z, pack P
    {
      int kvb = tkv * 16 + (l >> 4) * 4;
      float4 rn4;
      if constexpr (NCH == 2) rn4 = *(const float4*)&Nl[t * KB + kvb];
      else rn4 = *(const float4*)(norms + t * KB + kvb);
#pragma unroll
      for (int a = 0; a < 2; ++a) {
        const f32x4& ac = a ? acc1 : acc0;
        float p0 = __expf(ac[0] * rn4.x);
        float p1 = __expf(ac[1] * rn4.y);
        float p2 = __expf(ac[2] * rn4.z);
        float p3 = __expf(ac[3] * rn4.w);
        za[a] += (p0 + p1) + (p2 + p3);
        u32 w01, w23;
        asm("v_cvt_pk_bf16_f32 %0, %1, %2" : "=v"(w01) : "v"(p0), "v"(p1));
        asm("v_cvt_pk_bf16_f32 %0, %1, %2" : "=v"(w23) : "v"(p2), "v"(p3));
        int q = (pq * 2 + a) * 16 + (l & 15);
        int pbyte = (q * 128 + kvb * 2) ^ ((q & 7) << 4);
        *(uint2*)((char*)Pl + pbyte) = (uint2){w01, w23};
      }
    }
    asm volatile("s_waitcnt lgkmcnt(0)" ::: "memory");  // P writes done
    __builtin_amdgcn_s_barrier();
    __builtin_amdgcn_sched_barrier(0);

    // ---- phase 2: O += P . V (wave owns d-block w*64; V from registers)
    {
      const char* plb = (const char*)Pl;
      bf16x8 pa[4][2];
#pragma unroll
      for (int q2 = 0; q2 < 4; ++q2) {
        int qr = q2 * 16 + (l & 15);
        int qswz = (qr & 7) << 4;
#pragma unroll
        for (int ks = 0; ks < 2; ++ks)
          pa[q2][ks] = *(const bf16x8*)(plb + ((qr * 128 + ks * 64 + hi16) ^ qswz));
      }
#pragma unroll
      for (int dt = 0; dt < 4; ++dt) {
#pragma unroll
        for (int ks = 0; ks < 2; ++ks) {
          union { uint4 q; bf16x8 v; } uu;
          uu.q = vreg[dt * 2 + ks];
#pragma unroll
          for (int q2 = 0; q2 < 4; ++q2)
            oacc[q2][dt] =
                __builtin_amdgcn_mfma_f32_16x16x32_bf16(pa[q2][ks], uu.v, oacc[q2][dt], 0, 0, 0);
        }
      }
    }
    // ---- end of tile: K(t+1) landed, all LDS ops retired
    asm volatile("s_waitcnt vmcnt(0) lgkmcnt(0)" ::: "memory");
    __builtin_amdgcn_s_barrier();
    __builtin_amdgcn_sched_barrier(0);
  }

  // ---- Z reduction: za[a] covers q-tile pq*2+a, cols (l&15), partial over kv16 tkv
  {
#pragma unroll
    for (int a = 0; a < 2; ++a) {
      float s = za[a];
      s += __shfl_xor(s, 16);
      s += __shfl_xor(s, 32);
      if (l < 16) Zred[w * 32 + a * 16 + l] = s;
    }
  }
  __syncthreads();

  if constexpr (NCH == 2) {
    if (tid < QB) {
      int g = tid >> 4, p_ = g >> 1, a_ = g & 1;
      float s = 0.f;
#pragma unroll
      for (int tk = 0; tk < 4; ++tk) s += Zred[(tk * 2 + p_) * 32 + a_ * 16 + (tid & 15)];
      Zpart[chunk * NB + qblk * QB + tid] = s;
    }
    float* op = Opart + (size_t)chunk * NB * ND;
#pragma unroll
    for (int q2 = 0; q2 < 4; ++q2)
#pragma unroll
      for (int dt = 0; dt < 4; ++dt) {
        int d = w * 64 + dt * 16 + (l & 15);
#pragma unroll
        for (int r = 0; r < 4; ++r) {
          int q = qblk * QB + q2 * 16 + (l >> 4) * 4 + r;
          op[(size_t)q * ND + d] = oacc[q2][dt][r];
        }
      }
  } else {
    if (tid < QB) {
      int g = tid >> 4, p_ = g >> 1, a_ = g & 1;
      float s = 0.f;
#pragma unroll
      for (int tk = 0; tk < 4; ++tk) s += Zred[(tk * 2 + p_) * 32 + a_ * 16 + (tid & 15)];
      Zfin[tid] = s;
    }
    __syncthreads();
#pragma unroll
    for (int q2 = 0; q2 < 4; ++q2) {
      float rz[4];
#pragma unroll
      for (int r = 0; r < 4; ++r) rz[r] = 1.0f / Zfin[q2 * 16 + (l >> 4) * 4 + r];
#pragma unroll
      for (int dt = 0; dt < 4; ++dt) {
        int d = w * 64 + dt * 16 + (l & 15);
#pragma unroll
        for (int r = 0; r < 4; ++r) {
          int q = qblk * QB + q2 * 16 + (l >> 4) * 4 + r;
          out[(size_t)q * ND + d] = oacc[q2][dt][r] * rz[r];
        }
      }
    }
  }
}

// ---------------- combine (fast path): out = (O0+O1)/(Z0+Z1) ----------------
__global__ __launch_bounds__(256) void combine_kernel(const float* __restrict__ Opart,
                                                      const float* __restrict__ Zpart,
                                                      float* __restrict__ out) {
  size_t idx = ((size_t)blockIdx.x * 256 + threadIdx.x) * 4;
  int row = (int)(idx >> 9);
  float rz = 1.0f / (Zpart[row] + Zpart[NB + row]);
  float4 a = *(const float4*)(Opart + idx);
  float4 b = *(const float4*)(Opart + (size_t)NB * ND + idx);
  float4 o = {(a.x + b.x) * rz, (a.y + b.y) * rz, (a.z + b.z) * rz, (a.w + b.w) * rz};
  *(float4*)(out + idx) = o;
}

extern "C" void kernel_launch(void* const* d_in, const int* in_sizes, int n_in,
                              void* d_out, int out_size, void* d_ws, size_t ws_size,
                              hipStream_t stream) {
  const float* x = (const float*)d_in[0];
  float* outp = (float*)d_out;

  char* ws = (char*)d_ws;
  const size_t img_bytes = (size_t)NB * ND * 2;  // 8 MB each
  float* norms = (float*)ws;                     // 32 KB
  u16* Kimg = (u16*)(ws + 32768);
  u16* Vfrag = (u16*)(ws + 32768 + img_bytes);
  size_t base = 32768 + 2 * img_bytes;           // 16.03 MB
  float* Zpart = (float*)(ws + base);            // 64 KB
  float* Opart = (float*)(ws + base + 65536);    // 32 MB (f32, 2 planes)
  size_t need = base + 65536 + (size_t)2 * NB * ND * 4;

  prep_norms<<<NB / 4, 256, 0, stream>>>(x, norms);
  prep_images<<<NTILES, 256, 0, stream>>>(x, Kimg, Vfrag);
  if (ws_size >= need) {
    attn_kernel<2><<<256, 512, 0, stream>>>(x, Kimg, Vfrag, norms, Opart, Zpart, nullptr);
    combine_kernel<<<(NB * ND) / 1024, 256, 0, stream>>>(Opart, Zpart, outp);
  } else {
    attn_kernel<1><<<128, 512, 0, stream>>>(x, Kimg, Vfrag, norms, nullptr, nullptr, outp);
  }
}